// Round 4
// baseline (420.977 us; speedup 1.0000x reference)
//
#include <hip/hip_runtime.h>
#include <math.h>

#define BB 8
#define TT 4096
#define TP1 4097
#define HH 1024
#define NHD 16

__device__ __forceinline__ float dot4(const float4& a, const float4& b) {
  return a.x*b.x + a.y*b.y + a.z*b.z + a.w*b.w;
}

// ---------------- K1: qbuf[b][j] = 0.125*(cell[b,:]·Wq[j,:] + bq[j]) ----------------
__global__ __launch_bounds__(256) void k_q(const float* __restrict__ cell,
                                           const float* __restrict__ Wq,
                                           const float* __restrict__ bq,
                                           float* __restrict__ qbuf) {
  __shared__ float cs[BB * HH];  // 32 KB
  int tid = threadIdx.x;
  #pragma unroll
  for (int m = 0; m < 8; m++) {
    int idx4 = tid + (m << 8);
    ((float4*)cs)[idx4] = ((const float4*)cell)[idx4];
  }
  __syncthreads();
  int jj = tid >> 6, lane = tid & 63;
  int j = blockIdx.x * 4 + jj;
  float acc[BB];
  #pragma unroll
  for (int b = 0; b < BB; b++) acc[b] = 0.f;
  #pragma unroll
  for (int k = 0; k < 4; k++) {
    int i = (k << 8) + (lane << 2);
    float4 w = *(const float4*)&Wq[(size_t)j * HH + i];
    #pragma unroll
    for (int b = 0; b < BB; b++) acc[b] += dot4(w, *(const float4*)&cs[b * HH + i]);
  }
  #pragma unroll
  for (int b = 0; b < BB; b++) {
    acc[b] += __shfl_xor(acc[b], 1);  acc[b] += __shfl_xor(acc[b], 2);
    acc[b] += __shfl_xor(acc[b], 4);  acc[b] += __shfl_xor(acc[b], 8);
    acc[b] += __shfl_xor(acc[b], 16); acc[b] += __shfl_xor(acc[b], 32);
  }
  if (lane == 0) {
    float bqv = bq[j];
    #pragma unroll
    for (int b = 0; b < BB; b++) qbuf[b * HH + j] = 0.125f * (acc[b] + bqv);
  }
}

// ---------------- K2: qWkT[b][i][h] = sum_d qbuf[b][h*64+d]*Wk[h*64+d][i] ----------------
__global__ __launch_bounds__(256) void k_qwk(const float* __restrict__ qbuf,
                                             const float* __restrict__ Wk,
                                             const float* __restrict__ bk,
                                             float* __restrict__ qWkT,
                                             float* __restrict__ qbk) {
  __shared__ float q_s[BB * 64];
  __shared__ float red[4 * 64 * 9];  // padded +1
  int tid = threadIdx.x;
  int h = blockIdx.x >> 4, ic = blockIdx.x & 15;
  if (tid < 128) {
    int b = tid >> 4, dq = tid & 15;
    ((float4*)q_s)[tid] = ((const float4*)qbuf)[(b << 8) + (h << 4) + dq];
  }
  __syncthreads();
  int dg = tid >> 6, lane = tid & 63;
  int i = (ic << 6) + lane;
  float acc[BB];
  #pragma unroll
  for (int b = 0; b < BB; b++) acc[b] = 0.f;
  #pragma unroll
  for (int dd = 0; dd < 16; dd++) {
    int d = (dg << 4) + dd;
    float wk = Wk[(size_t)((h << 6) + d) * HH + i];
    #pragma unroll
    for (int b = 0; b < BB; b++) acc[b] += q_s[(b << 6) + d] * wk;
  }
  #pragma unroll
  for (int b = 0; b < BB; b++) red[((dg << 6) + lane) * 9 + b] = acc[b];
  __syncthreads();
  #pragma unroll
  for (int r = 0; r < 2; r++) {
    int o = tid + (r << 8);           // 512 outputs = 64 i x 8 b
    int il = o >> 3, b = o & 7;
    float s = 0.f;
    #pragma unroll
    for (int g = 0; g < 4; g++) s += red[((g << 6) + il) * 9 + b];
    qWkT[((size_t)(b << 10) + (ic << 6) + il) * NHD + h] = s;
  }
  if (ic == 0 && tid < 8) {
    float s = 0.f;
    for (int d = 0; d < 64; d++) s += q_s[(tid << 6) + d] * bk[(h << 6) + d];
    qbk[tid * NHD + h] = s;
  }
}

// ---------------- K3 (fused): per 64-row tile: scores+exp, then ctx outer-product partial ----------------
// grid 512 = b(8) x tile(64); block 256 = 4 waves.
// Phase 1: lane = t-row, wave w owns 16 cols of each 64-col chunk (qWkT wave-uniform -> s_loads).
//   Pipelined: loads for chunk c+2 issue BEFORE compute(c); c+1's data (in regs) ds_written after.
// Phase 2: 4 sub-passes of 16 rows x 1024 cols staged to LDS (fully coalesced);
//   thread owns i-quad (tid*4), acc4[16h] in VGPRs; tile-owned ctxpart slice (no atomics).
__device__ __forceinline__ void compute_chunk(const float* kv_s, const float* __restrict__ qb,
                                              int lane, int w, float* acc) {
  float4 kv[4];
  #pragma unroll
  for (int cq = 0; cq < 4; cq++)
    kv[cq] = *(const float4*)&kv_s[lane * 68 + (w << 4) + (cq << 2)];
  #pragma unroll
  for (int cq = 0; cq < 4; cq++) {
    const float* qp = qb + (cq << 6);
    #pragma unroll
    for (int h = 0; h < NHD; h++)
      acc[h] += kv[cq].x * qp[h] + kv[cq].y * qp[NHD + h] +
                kv[cq].z * qp[2 * NHD + h] + kv[cq].w * qp[3 * NHD + h];
  }
}

__global__ __launch_bounds__(256) void k_tile(const float* __restrict__ hid,
                                              const float* __restrict__ qWkT,
                                              const float* __restrict__ qbk,
                                              const int* __restrict__ mask,
                                              float* __restrict__ ctxpart,
                                              float* __restrict__ Spart) {
  __shared__ float smem[16 * 1024];  // 64 KB: ph1 kv0[0..4351], kv1[4352..8703], red[8704..12799]; ph2 full
  __shared__ float e_sh[64 * NHD];   // 4 KB, persists into phase 2
  __shared__ float qbk_s[NHD];
  int tid = threadIdx.x;
  int b = blockIdx.x >> 6, tile = blockIdx.x & 63;
  int t0 = tile << 6;
  if (tid < NHD) qbk_s[tid] = qbk[b * NHD + tid];
  int w = __builtin_amdgcn_readfirstlane(tid >> 6);
  int lane = tid & 63;
  const float* src = hid + ((size_t)(b * TP1) + t0) * HH;
  const float* qB = qWkT + (((size_t)(b << 10) + (w << 4)) << 4);

  float* kv0 = smem;
  float* kv1 = smem + 4352;
  int r_[4], c_[4];
  #pragma unroll
  for (int m = 0; m < 4; m++) { int idx = tid + (m << 8); r_[m] = idx >> 4; c_[m] = idx & 15; }

  float acc[NHD];
  #pragma unroll
  for (int h = 0; h < NHD; h++) acc[h] = 0.f;

  // ---- phase 1: pipelined chunk loop ----
  float4 rgA[4], rgB[4];
  #pragma unroll
  for (int m = 0; m < 4; m++) rgA[m] = *(const float4*)&src[(size_t)r_[m] * HH + (c_[m] << 2)];
  #pragma unroll
  for (int m = 0; m < 4; m++) *(float4*)&kv0[r_[m] * 68 + (c_[m] << 2)] = rgA[m];
  __syncthreads();
  #pragma unroll
  for (int m = 0; m < 4; m++) rgA[m] = *(const float4*)&src[(size_t)r_[m] * HH + 64 + (c_[m] << 2)];

  for (int cc = 0; cc < 16; cc += 2) {
    if (cc + 2 < 16) {
      #pragma unroll
      for (int m = 0; m < 4; m++)
        rgB[m] = *(const float4*)&src[(size_t)r_[m] * HH + ((cc + 2) << 6) + (c_[m] << 2)];
    }
    compute_chunk(kv0, qB + ((size_t)cc << 10), lane, w, acc);
    #pragma unroll
    for (int m = 0; m < 4; m++) *(float4*)&kv1[r_[m] * 68 + (c_[m] << 2)] = rgA[m];
    __syncthreads();
    if (cc + 3 < 16) {
      #pragma unroll
      for (int m = 0; m < 4; m++)
        rgA[m] = *(const float4*)&src[(size_t)r_[m] * HH + ((cc + 3) << 6) + (c_[m] << 2)];
    }
    compute_chunk(kv1, qB + ((size_t)(cc + 1) << 10), lane, w, acc);
    if (cc + 2 < 16) {
      #pragma unroll
      for (int m = 0; m < 4; m++) *(float4*)&kv0[r_[m] * 68 + (c_[m] << 2)] = rgB[m];
    }
    __syncthreads();
  }

  // ---- epilogue: reduce 4 wave-partials, mask, exp, e_sh + Spart ----
  float* red = smem + 8704;
  #pragma unroll
  for (int h4 = 0; h4 < 4; h4++)
    *(float4*)&red[((w << 6) + lane) * NHD + (h4 << 2)] =
        make_float4(acc[h4 * 4], acc[h4 * 4 + 1], acc[h4 * 4 + 2], acc[h4 * 4 + 3]);
  __syncthreads();
  {
    int row = tid >> 2, hq = tid & 3;
    float4 s = make_float4(0.f, 0.f, 0.f, 0.f);
    #pragma unroll
    for (int ww = 0; ww < 4; ww++) {
      float4 r = *(const float4*)&red[((ww << 6) + row) * NHD + (hq << 2)];
      s.x += r.x; s.y += r.y; s.z += r.z; s.w += r.w;
    }
    int mk = mask[b * TT + t0 + row];
    float4 e;
    e.x = mk ? __expf(s.x + qbk_s[hq * 4 + 0]) : 0.f;
    e.y = mk ? __expf(s.y + qbk_s[hq * 4 + 1]) : 0.f;
    e.z = mk ? __expf(s.z + qbk_s[hq * 4 + 2]) : 0.f;
    e.w = mk ? __expf(s.w + qbk_s[hq * 4 + 3]) : 0.f;
    *(float4*)&e_sh[(row << 4) + (hq << 2)] = e;
  }
  __syncthreads();
  if (tid < 64) {
    int g = tid >> 4, h2 = tid & 15;
    float s2 = 0.f;
    #pragma unroll
    for (int j = 0; j < 16; j++) s2 += e_sh[((g + (j << 2)) << 4) + h2];
    s2 += __shfl_xor(s2, 16);
    s2 += __shfl_xor(s2, 32);
    if (tid < 16) Spart[(size_t)((b << 6) + tile) * NHD + h2] = s2;
  }

  // ---- phase 2: ctx partial = e^T (16x64) x kv (64x1024), 4 sub-passes of 16 rows ----
  float4 tmp[16];
  #pragma unroll
  for (int j = 0; j < 16; j++) {  // prefetch sub-pass 0 (overlaps epilogue)
    int idx = tid + (j << 8);
    tmp[j] = *(const float4*)&src[(size_t)(idx >> 8) * HH + ((idx & 255) << 2)];
  }
  float4 acc4[NHD];
  #pragma unroll
  for (int h = 0; h < NHD; h++) acc4[h] = make_float4(0.f, 0.f, 0.f, 0.f);

  for (int s = 0; s < 4; s++) {
    __syncthreads();  // prior sub-pass readers (or epilogue red readers) done
    #pragma unroll
    for (int j = 0; j < 16; j++) ((float4*)smem)[tid + (j << 8)] = tmp[j];
    __syncthreads();
    if (s < 3) {
      #pragma unroll
      for (int j = 0; j < 16; j++) {  // prefetch next sub-pass; overlaps compute below
        int idx = tid + (j << 8);
        tmp[j] = *(const float4*)&src[(size_t)(((s + 1) << 4) + (idx >> 8)) * HH + ((idx & 255) << 2)];
      }
    }
    #pragma unroll
    for (int r = 0; r < 16; r++) {
      float4 kv4 = ((const float4*)smem)[(r << 8) + tid];
      const float* ep = &e_sh[(((s << 4) + r) << 4)];
      float4 e0 = *(const float4*)&ep[0];
      float4 e1 = *(const float4*)&ep[4];
      float4 e2 = *(const float4*)&ep[8];
      float4 e3 = *(const float4*)&ep[12];
      acc4[0].x += e0.x*kv4.x; acc4[0].y += e0.x*kv4.y; acc4[0].z += e0.x*kv4.z; acc4[0].w += e0.x*kv4.w;
      acc4[1].x += e0.y*kv4.x; acc4[1].y += e0.y*kv4.y; acc4[1].z += e0.y*kv4.z; acc4[1].w += e0.y*kv4.w;
      acc4[2].x += e0.z*kv4.x; acc4[2].y += e0.z*kv4.y; acc4[2].z += e0.z*kv4.z; acc4[2].w += e0.z*kv4.w;
      acc4[3].x += e0.w*kv4.x; acc4[3].y += e0.w*kv4.y; acc4[3].z += e0.w*kv4.z; acc4[3].w += e0.w*kv4.w;
      acc4[4].x += e1.x*kv4.x; acc4[4].y += e1.x*kv4.y; acc4[4].z += e1.x*kv4.z; acc4[4].w += e1.x*kv4.w;
      acc4[5].x += e1.y*kv4.x; acc4[5].y += e1.y*kv4.y; acc4[5].z += e1.y*kv4.z; acc4[5].w += e1.y*kv4.w;
      acc4[6].x += e1.z*kv4.x; acc4[6].y += e1.z*kv4.y; acc4[6].z += e1.z*kv4.z; acc4[6].w += e1.z*kv4.w;
      acc4[7].x += e1.w*kv4.x; acc4[7].y += e1.w*kv4.y; acc4[7].z += e1.w*kv4.z; acc4[7].w += e1.w*kv4.w;
      acc4[8].x += e2.x*kv4.x; acc4[8].y += e2.x*kv4.y; acc4[8].z += e2.x*kv4.z; acc4[8].w += e2.x*kv4.w;
      acc4[9].x += e2.y*kv4.x; acc4[9].y += e2.y*kv4.y; acc4[9].z += e2.y*kv4.z; acc4[9].w += e2.y*kv4.w;
      acc4[10].x += e2.z*kv4.x; acc4[10].y += e2.z*kv4.y; acc4[10].z += e2.z*kv4.z; acc4[10].w += e2.z*kv4.w;
      acc4[11].x += e2.w*kv4.x; acc4[11].y += e2.w*kv4.y; acc4[11].z += e2.w*kv4.z; acc4[11].w += e2.w*kv4.w;
      acc4[12].x += e3.x*kv4.x; acc4[12].y += e3.x*kv4.y; acc4[12].z += e3.x*kv4.z; acc4[12].w += e3.x*kv4.w;
      acc4[13].x += e3.y*kv4.x; acc4[13].y += e3.y*kv4.y; acc4[13].z += e3.y*kv4.z; acc4[13].w += e3.y*kv4.w;
      acc4[14].x += e3.z*kv4.x; acc4[14].y += e3.z*kv4.y; acc4[14].z += e3.z*kv4.z; acc4[14].w += e3.z*kv4.w;
      acc4[15].x += e3.w*kv4.x; acc4[15].y += e3.w*kv4.y; acc4[15].z += e3.w*kv4.z; acc4[15].w += e3.w*kv4.w;
    }
  }
  float* dst = ctxpart + (((size_t)((b << 6) + tile)) << 14) + (tid << 2);
  #pragma unroll
  for (int h = 0; h < NHD; h++) *(float4*)&dst[h << 10] = acc4[h];
}

// ---------------- K4: Sinv[b][h] = 1 / sum_tiles Spart ----------------
__global__ void k_sinv(const float* __restrict__ Spart, float* __restrict__ Sinv) {
  int tid = threadIdx.x;  // 128
  float s = 0.f;
  for (int c = 0; c < 64; c++) s += Spart[(size_t)((tid >> 4) * 64 + c) * NHD + (tid & 15)];
  Sinv[tid] = 1.f / s;
}

// ---------------- K5: ctxin[b][h][i] = sum over 64 tile-partials ----------------
// grid 512 = b(8) x h(16) x qi(4); block 256; thread = one i, 64 strided dword loads, unroll 8.
__global__ __launch_bounds__(256) void k_reduce(const float* __restrict__ ctxpart,
                                                float* __restrict__ ctxin) {
  int tid = threadIdx.x;
  int b = blockIdx.x >> 6, h = (blockIdx.x >> 2) & 15, qi = blockIdx.x & 3;
  int i = (qi << 8) + tid;
  const float* p = ctxpart + ((size_t)((b << 6) * NHD + h) << 10) + i;
  float s = 0.f;
  #pragma unroll 8
  for (int t = 0; t < 64; t++) s += p[(size_t)t << 14];
  ctxin[(size_t)(((b << 4) + h) << 10) + i] = s;
}

// ---------------- K6: out[b][j] = Sinv[b][h]*(Wv[j,:]·ctxin[b][h][:]) + bv[j] ----------------
__global__ __launch_bounds__(256) void k_out(const float* __restrict__ Wv,
                                             const float* __restrict__ bv,
                                             const float* __restrict__ ctxin,
                                             const float* __restrict__ Sinv,
                                             float* __restrict__ out) {
  __shared__ float cs[BB * HH];  // 32 KB
  int tid = threadIdx.x;
  int h = blockIdx.x >> 4;
  int j0 = blockIdx.x * 4;
  #pragma unroll
  for (int m = 0; m < 8; m++) {
    int idx4 = tid + (m << 8);
    int b = idx4 >> 8, i4 = idx4 & 255;
    ((float4*)cs)[idx4] = ((const float4*)ctxin)[(((b << 4) + h) << 8) + i4];
  }
  __syncthreads();
  int jj = tid >> 6, lane = tid & 63;
  int j = j0 + jj;
  float acc[BB];
  #pragma unroll
  for (int b = 0; b < BB; b++) acc[b] = 0.f;
  #pragma unroll
  for (int k = 0; k < 4; k++) {
    int i = (k << 8) + (lane << 2);
    float4 w = *(const float4*)&Wv[(size_t)j * HH + i];
    #pragma unroll
    for (int b = 0; b < BB; b++) acc[b] += dot4(w, *(const float4*)&cs[b * HH + i]);
  }
  #pragma unroll
  for (int b = 0; b < BB; b++) {
    acc[b] += __shfl_xor(acc[b], 1);  acc[b] += __shfl_xor(acc[b], 2);
    acc[b] += __shfl_xor(acc[b], 4);  acc[b] += __shfl_xor(acc[b], 8);
    acc[b] += __shfl_xor(acc[b], 16); acc[b] += __shfl_xor(acc[b], 32);
  }
  if (lane == 0) {
    float bvj = bv[j];
    #pragma unroll
    for (int b = 0; b < BB; b++)
      out[b * HH + j] = Sinv[b * NHD + h] * acc[b] + bvj;
  }
}

extern "C" void kernel_launch(void* const* d_in, const int* in_sizes, int n_in,
                              void* d_out, int out_size, void* d_ws, size_t ws_size,
                              hipStream_t stream) {
  const float* hid  = (const float*)d_in[0];  // (8, 4097, 1024)
  const float* cell = (const float*)d_in[1];  // (8, 1024)
  const float* Wq   = (const float*)d_in[2];
  const float* bq   = (const float*)d_in[3];
  const float* Wk   = (const float*)d_in[4];
  const float* bk   = (const float*)d_in[5];
  const float* Wv   = (const float*)d_in[6];
  const float* bv   = (const float*)d_in[7];
  const int*  mask  = (const int*)d_in[8];    // (8, 4096)
  float* out = (float*)d_out;                 // (8, 1024)

  float* ws = (float*)d_ws;
  float* qbuf    = ws;             // 8192
  float* qWkT    = ws + 8192;      // 131072  [b][i][16]
  float* qbk     = ws + 139264;    // 128
  float* Spart   = ws + 139392;    // 8192
  float* Sinv    = ws + 147584;    // 128
  float* ctxin   = ws + 147712;    // 131072  [b][h][1024]
  float* ctxpart = ws + 278784;    // 8388608 [b*64+tile][h][1024] (32 MB)

  hipLaunchKernelGGL(k_q,      dim3(256), dim3(256), 0, stream, cell, Wq, bq, qbuf);
  hipLaunchKernelGGL(k_qwk,    dim3(256), dim3(256), 0, stream, qbuf, Wk, bk, qWkT, qbk);
  hipLaunchKernelGGL(k_tile,   dim3(512), dim3(256), 0, stream, hid, qWkT, qbk, mask, ctxpart, Spart);
  hipLaunchKernelGGL(k_sinv,   dim3(1),   dim3(128), 0, stream, Spart, Sinv);
  hipLaunchKernelGGL(k_reduce, dim3(512), dim3(256), 0, stream, ctxpart, ctxin);
  hipLaunchKernelGGL(k_out,    dim3(256), dim3(256), 0, stream, Wv, bv, ctxin, Sinv, out);
}